// Round 9
// baseline (898.303 us; speedup 1.0000x reference)
//
#include <hip/hip_runtime.h>
#include <hip/hip_bf16.h>
#include <hip/hip_fp16.h>

#define NN 50000
#define INCH 512
#define OUTCH 64
#define NTILES 3125       // 50000 / 16 (exact)
#define GB 782            // gemm blocks: ceil(3125 tiles / 4 waves)
#define SB 512            // append blocks after gemm blocks
#define RPB 32            // rows per bucket
#define NBUCKET 1563      // ceil(50000 / 32)
#define BCAP 704          // records/bucket cap: Poisson(512) + 8.5 sigma

typedef __attribute__((ext_vector_type(8))) short short8;
typedef __attribute__((ext_vector_type(4))) float floatx4;
typedef unsigned long long u64;

__device__ __forceinline__ unsigned packbf2(float a, float b) {
    __hip_bfloat162 h = __float22bfloat162_rn(make_float2(a, b));  // v_cvt_pk_bf16_f32 RNE
    unsigned r;
    __builtin_memcpy(&r, &h, 4);
    return r;
}
__device__ __forceinline__ unsigned short f2bf(float f) {
    unsigned u = __float_as_uint(f);
    return (unsigned short)((u + 0x7FFFu + ((u >> 16) & 1u)) >> 16);  // RNE
}
__device__ __forceinline__ float bf2f(unsigned short u) {
    return __uint_as_float(((unsigned)u) << 16);
}

// ---------------- prep: zero bucket tails + convert W fp32 [k][n] -> bf16 [n][k] -------
__global__ __launch_bounds__(256) void prep_kernel(const float* __restrict__ W,
                                                   unsigned short* __restrict__ Wbf,
                                                   int* __restrict__ btail) {
    const int i = blockIdx.x * 256 + threadIdx.x;
    if (i < NBUCKET) btail[i] = 0;
    if (i < INCH * OUTCH) {
        const int k = i >> 6;          // W is [k][n], read coalesced
        const int n = i & 63;
        Wbf[n * INCH + k] = f2bf(W[i]);
    }
}

// ---------------- fused: [blocks 0..GB) gemm | [GB..GB+SB) bucket append ------------
// Append replaces the random ELL scatter: records go to per-32-row bucket
// tails. Only ~1563 line-fronts (~100 KB) are ever write-active, so stores
// are append-dense instead of 128 B/edge write-allocate churn (the measured
// 107 MB that clocked every prior scatter variant at ~77 us).
__global__ __launch_bounds__(256, 4) void fused_gemm_scatter(
        const float* __restrict__ A, const unsigned short* __restrict__ Wbf,
        unsigned short* __restrict__ C,
        const int* __restrict__ rows, const int* __restrict__ cols,
        const float* __restrict__ vals, int* __restrict__ btail,
        u64* __restrict__ buckets, int E_) {
    __shared__ unsigned short ldsT[4][16 * 64];   // 2 KB per wave (gemm only)
    const int t = threadIdx.x;

    if (blockIdx.x >= GB) {
        // ---------- bucket-append part ----------
        for (int e = (blockIdx.x - GB) * 256 + t; e < E_; e += SB * 256) {
            const int r = __builtin_nontemporal_load(rows + e);
            const int c = __builtin_nontemporal_load(cols + e);
            const float v = __builtin_nontemporal_load(vals + e);
            const unsigned short hv = __half_as_ushort(__float2half(v));
            const u64 rec = (u64)(unsigned)(r & 0xFFFF)
                          | ((u64)(unsigned)(c & 0xFFFF) << 16)
                          | ((u64)hv << 32);
            const int b = r >> 5;                       // r/RPB
            const int pos = atomicAdd(&btail[b], 1);
            if (pos < BCAP)
                buckets[(size_t)b * BCAP + pos] = rec;  // append-dense store
        }
        return;
    }

    // ---------- gemm part ----------
    const int lane = t & 63;
    const int wave = t >> 6;
    const int tile = blockIdx.x * 4 + wave;
    if (tile >= NTILES) return;
    const int rbase = tile * 16;
    const int frow = lane & 15;
    const int quad = lane >> 4;
    const float* Ap = A + (size_t)(rbase + frow) * INCH + quad * 8;
    const unsigned short* Bp = Wbf + frow * INCH + quad * 8;

    floatx4 acc[4] = {floatx4{0,0,0,0}, floatx4{0,0,0,0}, floatx4{0,0,0,0}, floatx4{0,0,0,0}};

#pragma unroll
    for (int c = 0; c < 16; ++c) {
        const floatx4 a0 = __builtin_nontemporal_load((const floatx4*)(Ap + c * 32));
        const floatx4 a1 = __builtin_nontemporal_load((const floatx4*)(Ap + c * 32 + 4));
        short8 bfr[4];
#pragma unroll
        for (int f = 0; f < 4; ++f)   // Wbf hot: normal cached loads
            bfr[f] = *(const short8*)(Bp + (size_t)f * 16 * INCH + c * 32);
        uint4 au;
        au.x = packbf2(a0[0], a0[1]);
        au.y = packbf2(a0[2], a0[3]);
        au.z = packbf2(a1[0], a1[1]);
        au.w = packbf2(a1[2], a1[3]);
        const short8 af = *(const short8*)&au;
#pragma unroll
        for (int f = 0; f < 4; ++f)
            acc[f] = __builtin_amdgcn_mfma_f32_16x16x32_bf16(af, bfr[f], acc[f], 0, 0, 0);
    }

    // C/D layout: col = f*16 + frow, row = quad*4 + reg   [m89]
    unsigned short* myT = ldsT[wave];
#pragma unroll
    for (int f = 0; f < 4; ++f)
#pragma unroll
        for (int reg = 0; reg < 4; ++reg)
            myT[(quad * 4 + reg) * 64 + f * 16 + frow] = f2bf(acc[f][reg]);
    // wave-local: ds ordering handled by lgkmcnt, no barrier needed
    unsigned short* Cw = C + (size_t)rbase * OUTCH;
#pragma unroll
    for (int it = 0; it < 2; ++it) {
        const short8 v = *(const short8*)&myT[it * 512 + lane * 8];
        __builtin_nontemporal_store(v, (short8*)(Cw + it * 512 + lane * 8));
    }
}

// ---------------- SpMM directly off buckets: one block per 32-row bucket ----------
// LDS fp32 accumulator (stride 65 -> bank = (row+ch)%32, random rows spread
// banks). Per record: 4 threads x 16 ch gather x[col] (128 B contiguous, the
// irreducible random-line cost) and ds-atomic-fma into the accumulator.
// Output written coalesced, block-exclusive. No ELL, no deg, no sentinels.
template <bool LAST>
__global__ __launch_bounds__(256) void spmm_bucket(
        const int* __restrict__ btail, const u64* __restrict__ buckets,
        const unsigned short* __restrict__ xin, void* __restrict__ xout_,
        const float* __restrict__ bias) {
    __shared__ float acc[RPB * 65];               // 8320 B
    const int t = threadIdx.x;
    const int b = blockIdx.x;                     // grid = NBUCKET
    const int rbase = b * RPB;

    for (int j = t; j < RPB * 65; j += 256) acc[j] = 0.f;
    __syncthreads();

    int n = btail[b];
    n = n < BCAP ? n : BCAP;
    const u64* base = buckets + (size_t)b * BCAP;
    const int g = t >> 2;                         // record group 0..63
    const int cl = t & 3;                         // 16-ch slice within record

    for (int i = g; i < n; i += 64) {
        const u64 rec = base[i];                  // 4-lane broadcast load
        const int rloc = ((int)rec & 0xFFFF) - rbase;
        const int col = (int)(rec >> 16) & 0xFFFF;
        const float v = __half2float(__ushort_as_half((unsigned short)(rec >> 32)));
        const unsigned short* xp = xin + (size_t)col * OUTCH + cl * 16;
        const short8 xv0 = *(const short8*)xp;
        const short8 xv1 = *(const short8*)(xp + 8);
        float* ap = acc + rloc * 65 + cl * 16;
#pragma unroll
        for (int k = 0; k < 8; ++k)
            atomicAdd(&ap[k], v * bf2f((unsigned short)xv0[k]));
#pragma unroll
        for (int k = 0; k < 8; ++k)
            atomicAdd(&ap[8 + k], v * bf2f((unsigned short)xv1[k]));
    }
    __syncthreads();

    // write-out: 32 rows x 64 ch; thread = (row = t>>3, 8-ch group = t&7)
    const int row = rbase + (t >> 3);
    const int chb = (t & 7) * 8;
    if (row < NN) {                               // last bucket: rows 49984..50015
        const float* ap = acc + (t >> 3) * 65 + chb;
        if (LAST) {
            const floatx4 b0 = *(const floatx4*)(bias + chb);
            const floatx4 b1 = *(const floatx4*)(bias + chb + 4);
            floatx4 o0 = {ap[0] + b0[0], ap[1] + b0[1], ap[2] + b0[2], ap[3] + b0[3]};
            floatx4 o1 = {ap[4] + b1[0], ap[5] + b1[1], ap[6] + b1[2], ap[7] + b1[3]};
            float* op = (float*)xout_ + (size_t)row * OUTCH + chb;
            __builtin_nontemporal_store(o0, (floatx4*)op);
            __builtin_nontemporal_store(o1, (floatx4*)(op + 4));
        } else {
            short8 o;
#pragma unroll
            for (int k = 0; k < 8; ++k) o[k] = (short)f2bf(ap[k]);
            __builtin_nontemporal_store(
                o, (short8*)((unsigned short*)xout_ + (size_t)row * OUTCH + chb));
        }
    }
}

extern "C" void kernel_launch(void* const* d_in, const int* in_sizes, int n_in,
                              void* d_out, int out_size, void* d_ws, size_t ws_size,
                              hipStream_t stream) {
    const int*   adj   = (const int*)d_in[0];     // [2, E]
    const float* avals = (const float*)d_in[1];   // [E]
    const float* feat  = (const float*)d_in[2];   // [N, 512]
    const float* W     = (const float*)d_in[3];   // [512, 64]
    const float* bias  = (const float*)d_in[4];   // [64]
    float* out = (float*)d_out;

    const int E_ = in_sizes[1];
    const int* rows = adj;
    const int* cols = adj + E_;

    // workspace layout (16B-aligned segments), total ~21.7 MB
    unsigned short* x0  = (unsigned short*)d_ws;             // N*64 bf16 (6.4 MB)
    unsigned short* x1  = x0 + (size_t)NN * OUTCH;           // N*64 bf16 (6.4 MB)
    unsigned short* Wbf = x1 + (size_t)NN * OUTCH;           // 64*512 bf16 (64 KB)
    u64* buckets = (u64*)(Wbf + (size_t)OUTCH * INCH);       // 1563*704 u64 (8.8 MB)
    int* btail = (int*)(buckets + (size_t)NBUCKET * BCAP);   // 1563 int

    // ---- prep: zero bucket tails + convert W to bf16 [n][k] ----
    prep_kernel<<<128, 256, 0, stream>>>(W, Wbf, btail);

    // ---- fused: dense projection (bf16 MFMA) + bucket append ----
    fused_gemm_scatter<<<GB + SB, 256, 0, stream>>>(feat, Wbf, x0, rows, cols, avals,
                                                    btail, buckets, E_);

    // ---- two SpMM hops off buckets; bias fused into the last ----
    spmm_bucket<false><<<NBUCKET, 256, 0, stream>>>(btail, buckets, x0, x1, nullptr);
    spmm_bucket<true><<<NBUCKET, 256, 0, stream>>>(btail, buckets, x1, out, bias);
}

// Round 10
// 258.987 us; speedup vs baseline: 3.4685x; 3.4685x over previous
//
#include <hip/hip_runtime.h>
#include <hip/hip_bf16.h>
#include <hip/hip_fp16.h>

#define NN 50000
#define INCH 512
#define OUTCH 64
#define NTILES 3125       // 50000 / 16 (exact)
#define MAXD 48           // ELL slots per row
#define GB 782            // gemm blocks: ceil(3125 tiles / 4 waves)
#define SB 512            // append blocks after gemm blocks
#define RPB 32            // rows per bucket
#define NBUCKET 1563      // ceil(50000 / 32)
#define NPART 8           // sub-buckets per bucket (one per XCD under round-robin)
#define BCAPP 112         // records per sub-bucket: Poisson(64) + 6 sigma
#define TSTR 16           // btail counter stride (64 B): no same-line atomic pileup

typedef __attribute__((ext_vector_type(8))) short short8;
typedef __attribute__((ext_vector_type(4))) float floatx4;
typedef unsigned long long u64;

__device__ __forceinline__ unsigned packbf2(float a, float b) {
    __hip_bfloat162 h = __float22bfloat162_rn(make_float2(a, b));  // v_cvt_pk_bf16_f32 RNE
    unsigned r;
    __builtin_memcpy(&r, &h, 4);
    return r;
}
__device__ __forceinline__ unsigned short f2bf(float f) {
    unsigned u = __float_as_uint(f);
    return (unsigned short)((u + 0x7FFFu + ((u >> 16) & 1u)) >> 16);  // RNE
}
__device__ __forceinline__ float bf2f(unsigned short u) {
    return __uint_as_float(((unsigned)u) << 16);
}

// ------------- prep: zero padded sub-bucket tails + convert W -> bf16 [n][k] ----------
__global__ __launch_bounds__(256) void prep_kernel(const float* __restrict__ W,
                                                   unsigned short* __restrict__ Wbf,
                                                   int* __restrict__ btail) {
    const int i = blockIdx.x * 256 + threadIdx.x;
    if (i < (NBUCKET * NPART * TSTR) / 4)   // 200064 ints = 50016 uint4
        *reinterpret_cast<uint4*>(btail + i * 4) = uint4{0u, 0u, 0u, 0u};
    if (i < INCH * OUTCH) {
        const int k = i >> 6;          // W is [k][n], read coalesced
        const int n = i & 63;
        Wbf[n * INCH + k] = f2bf(W[i]);
    }
}

// ---------------- fused: [blocks 0..GB) gemm | [GB..GB+SB) partitioned append --------
// Append is dense (no 128B/edge write-allocate churn). r9's two serialization
// bugs fixed: (1) sub-bucket per blockIdx&7 -> all writers of a front line sit
// on one XCD under round-robin dispatch (no cross-XCD line ping-pong; wrong
// mapping only costs speed, never correctness); (2) tail counters padded to
// 64 B each, <=64 atomics per counter (r9: 8192 same-line atomics/line).
__global__ __launch_bounds__(256, 4) void fused_gemm_scatter(
        const float* __restrict__ A, const unsigned short* __restrict__ Wbf,
        unsigned short* __restrict__ C,
        const int* __restrict__ rows, const int* __restrict__ cols,
        const float* __restrict__ vals, int* __restrict__ btail,
        u64* __restrict__ buckets, int E_) {
    __shared__ unsigned short ldsT[4][16 * 64];   // 2 KB per wave (gemm only)
    const int t = threadIdx.x;

    if (blockIdx.x >= GB) {
        const int s = blockIdx.x - GB;
        const int part = s & 7;                   // XCD-aligned under round-robin
        for (int e = s * 256 + t; e < E_; e += SB * 256) {
            const int r = __builtin_nontemporal_load(rows + e);
            const int c = __builtin_nontemporal_load(cols + e);
            const float v = __builtin_nontemporal_load(vals + e);
            const unsigned short hv = __half_as_ushort(__float2half(v));
            const u64 rec = (u64)(unsigned)(r & 0xFFFF)
                          | ((u64)(unsigned)(c & 0xFFFF) << 16)
                          | ((u64)hv << 32);
            const int sb = (r >> 5) * NPART + part;
            const int pos = atomicAdd(&btail[sb * TSTR], 1);
            if (pos < BCAPP)
                buckets[(size_t)sb * BCAPP + pos] = rec;
        }
        return;
    }

    // ---------- gemm part ----------
    const int lane = t & 63;
    const int wave = t >> 6;
    const int tile = blockIdx.x * 4 + wave;
    if (tile >= NTILES) return;
    const int rbase = tile * 16;
    const int frow = lane & 15;
    const int quad = lane >> 4;
    const float* Ap = A + (size_t)(rbase + frow) * INCH + quad * 8;
    const unsigned short* Bp = Wbf + frow * INCH + quad * 8;

    floatx4 acc[4] = {floatx4{0,0,0,0}, floatx4{0,0,0,0}, floatx4{0,0,0,0}, floatx4{0,0,0,0}};

#pragma unroll
    for (int c = 0; c < 16; ++c) {
        const floatx4 a0 = __builtin_nontemporal_load((const floatx4*)(Ap + c * 32));
        const floatx4 a1 = __builtin_nontemporal_load((const floatx4*)(Ap + c * 32 + 4));
        short8 bfr[4];
#pragma unroll
        for (int f = 0; f < 4; ++f)   // Wbf hot: normal cached loads
            bfr[f] = *(const short8*)(Bp + (size_t)f * 16 * INCH + c * 32);
        uint4 au;
        au.x = packbf2(a0[0], a0[1]);
        au.y = packbf2(a0[2], a0[3]);
        au.z = packbf2(a1[0], a1[1]);
        au.w = packbf2(a1[2], a1[3]);
        const short8 af = *(const short8*)&au;
#pragma unroll
        for (int f = 0; f < 4; ++f)
            acc[f] = __builtin_amdgcn_mfma_f32_16x16x32_bf16(af, bfr[f], acc[f], 0, 0, 0);
    }

    // C/D layout: col = f*16 + frow, row = quad*4 + reg   [m89]
    unsigned short* myT = ldsT[wave];
#pragma unroll
    for (int f = 0; f < 4; ++f)
#pragma unroll
        for (int reg = 0; reg < 4; ++reg)
            myT[(quad * 4 + reg) * 64 + f * 16 + frow] = f2bf(acc[f][reg]);
    // wave-local: ds ordering handled by lgkmcnt, no barrier needed
    unsigned short* Cw = C + (size_t)rbase * OUTCH;
#pragma unroll
    for (int it = 0; it < 2; ++it) {
        const short8 v = *(const short8*)&myT[it * 512 + lane * 8];
        __builtin_nontemporal_store(v, (short8*)(Cw + it * 512 + lane * 8));
    }
}

// ---------------- bucketize: block per bucket, buckets -> ELL slice + deg ----------
// ONE LDS atomic per record (slot assignment on 32 row-counters), record staged
// into the 6 KB LDS ELL slice, then written out fully coalesced. Replaces the
// random global ELL scatter (the 107 MB churn that clocked r8's fused at 77us).
__global__ __launch_bounds__(256) void bucketize(
        const int* __restrict__ btail, const u64* __restrict__ buckets,
        unsigned* __restrict__ ell, int* __restrict__ deg) {
    __shared__ int cnt[RPB];
    __shared__ __align__(16) unsigned stage[RPB * MAXD];   // 6 KB
    const int t = threadIdx.x;
    const int b = blockIdx.x;                  // grid = NBUCKET

    if (t < RPB) cnt[t] = 0;
    // stage needs no zero-init: slots >= deg are masked by spmm's sentinel
    for (int j = t; j < RPB * MAXD; j += 256) stage[j] = 0u;
    __syncthreads();

    for (int part = 0; part < NPART; ++part) {
        const int sb = b * NPART + part;
        int n = btail[sb * TSTR];
        n = n < BCAPP ? n : BCAPP;
        const u64* base = buckets + (size_t)sb * BCAPP;
        for (int i = t; i < n; i += 256) {
            const u64 rec = base[i];
            const int rloc = (int)rec & 31;    // row & 31 == row - 32*b
            const int slot = atomicAdd(&cnt[rloc], 1);
            if (slot < MAXD)
                stage[rloc * MAXD + slot] = (unsigned)(rec >> 16);  // col | hv<<16
        }
    }
    __syncthreads();

    // coalesced write-out: 6 KB ELL slice (rows 32b..32b+31 contiguous)
    uint4* dst = (uint4*)(ell + (size_t)b * RPB * MAXD);
    const uint4* src = (const uint4*)stage;
    for (int j = t; j < (RPB * MAXD) / 4; j += 256) dst[j] = src[j];
    const int row = b * RPB + t;
    if (t < RPB && row < NN) {
        int d = cnt[t];
        deg[row] = d < MAXD ? d : MAXD;
    }
}

// ---------------- SpMM over ELL: wave per row, 8 edge-slots x 8 ch-lanes ----------
// (unchanged from round 8: the proven ~56us/hop gather-floor kernel)
template <bool LAST>
__global__ __launch_bounds__(256) void spmm_full(const int* __restrict__ deg,
                                                 const unsigned* __restrict__ ell,
                                                 const unsigned short* __restrict__ xin,
                                                 void* __restrict__ xout_,
                                                 const float* __restrict__ bias) {
    const int t = threadIdx.x;
    const int lane = t & 63;
    const int eslot = lane >> 3;              // 0..7: edge slot group
    const int cg = lane & 7;                  // channel group: 8 ch (16B) each
    const int row = blockIdx.x * 4 + (t >> 6);   // grid = 12500, NN exact
    int d = deg[row];
    d = d < MAXD ? d : MAXD;
    const unsigned* eb = ell + (size_t)row * MAXD;

    unsigned p[6];
#pragma unroll
    for (int j = 0; j < 6; ++j)
        p[j] = __builtin_nontemporal_load(eb + eslot + 8 * j);
#pragma unroll
    for (int j = 0; j < 6; ++j)
        if (eslot + 8 * j >= d) p[j] = 0u;    // col 0, val 0 -> contributes 0

    const unsigned short* xh = xin + cg * 8;
    float acc[8] = {0.f, 0.f, 0.f, 0.f, 0.f, 0.f, 0.f, 0.f};

#pragma unroll
    for (int j = 0; j < 6; ++j) {
        if (d > 8 * j) {                      // wave-uniform round skip
            const unsigned P = p[j];
            const short8 xv = *(const short8*)(xh + (size_t)(P & 0xFFFFu) * OUTCH);
            const float v = __half2float(__ushort_as_half((unsigned short)(P >> 16)));
#pragma unroll
            for (int k = 0; k < 8; ++k)
                acc[k] = fmaf(v, bf2f((unsigned short)xv[k]), acc[k]);
        }
    }

#pragma unroll
    for (int k = 0; k < 8; ++k) {
        acc[k] += __shfl_xor(acc[k], 8, 64);
        acc[k] += __shfl_xor(acc[k], 16, 64);
        acc[k] += __shfl_xor(acc[k], 32, 64);
    }

    if (eslot == 0) {
        const int chb = cg * 8;
        if (LAST) {
            float* op = (float*)xout_ + (size_t)row * OUTCH + chb;
            const floatx4 b0 = *(const floatx4*)(bias + chb);
            const floatx4 b1 = *(const floatx4*)(bias + chb + 4);
            floatx4 o0, o1;
            o0[0] = acc[0] + b0[0]; o0[1] = acc[1] + b0[1];
            o0[2] = acc[2] + b0[2]; o0[3] = acc[3] + b0[3];
            o1[0] = acc[4] + b1[0]; o1[1] = acc[5] + b1[1];
            o1[2] = acc[6] + b1[2]; o1[3] = acc[7] + b1[3];
            __builtin_nontemporal_store(o0, (floatx4*)op);
            __builtin_nontemporal_store(o1, (floatx4*)(op + 4));
        } else {
            unsigned short* op = (unsigned short*)xout_ + (size_t)row * OUTCH + chb;
            short8 o;
#pragma unroll
            for (int k = 0; k < 8; ++k) o[k] = (short)f2bf(acc[k]);
            __builtin_nontemporal_store(o, (short8*)op);
        }
    }
}

extern "C" void kernel_launch(void* const* d_in, const int* in_sizes, int n_in,
                              void* d_out, int out_size, void* d_ws, size_t ws_size,
                              hipStream_t stream) {
    const int*   adj   = (const int*)d_in[0];     // [2, E]
    const float* avals = (const float*)d_in[1];   // [E]
    const float* feat  = (const float*)d_in[2];   // [N, 512]
    const float* W     = (const float*)d_in[3];   // [512, 64]
    const float* bias  = (const float*)d_in[4];   // [64]
    float* out = (float*)d_out;

    const int E_ = in_sizes[1];
    const int* rows = adj;
    const int* cols = adj + E_;

    // workspace layout (16B-aligned segments), total ~35 MB
    unsigned short* x0  = (unsigned short*)d_ws;             // N*64 bf16 (6.4 MB)
    unsigned short* x1  = x0 + (size_t)NN * OUTCH;           // N*64 bf16 (6.4 MB)
    unsigned short* Wbf = x1 + (size_t)NN * OUTCH;           // 64*512 bf16 (64 KB)
    unsigned* ell = (unsigned*)(Wbf + (size_t)OUTCH * INCH); // 1563*1536 u32 (9.6 MB)
    u64* buckets = (u64*)(ell + (size_t)NBUCKET * RPB * MAXD); // 1563*8*112 u64 (11.2 MB)
    int* btail = (int*)(buckets + (size_t)NBUCKET * NPART * BCAPP); // padded (800 KB)
    int* deg = btail + NBUCKET * NPART * TSTR;               // N int (200 KB)

    // ---- prep: zero padded tails + convert W to bf16 [n][k] ----
    prep_kernel<<<196, 256, 0, stream>>>(W, Wbf, btail);

    // ---- fused: dense projection (bf16 MFMA) + partitioned bucket append ----
    fused_gemm_scatter<<<GB + SB, 256, 0, stream>>>(feat, Wbf, x0, rows, cols, avals,
                                                    btail, buckets, E_);

    // ---- buckets -> ELL (coalesced) + deg ----
    bucketize<<<NBUCKET, 256, 0, stream>>>(btail, buckets, ell, deg);

    // ---- two SpMM hops; bias fused into the last ----
    spmm_full<false><<<NN / 4, 256, 0, stream>>>(deg, ell, x0, x1, nullptr);
    spmm_full<true><<<NN / 4, 256, 0, stream>>>(deg, ell, x1, out, bias);
}